// Round 8
// baseline (325.653 us; speedup 1.0000x reference)
//
#include <hip/hip_runtime.h>
#include <stdint.h>

#define N_ROWS 8192
#define D_DIM  1024
#define BK     64

typedef __attribute__((ext_vector_type(8)))  __bf16 bf16x8;
typedef __attribute__((ext_vector_type(16))) float  f32x16;

#define GLD16(gptr, lptr) __builtin_amdgcn_global_load_lds( \
    (const __attribute__((address_space(1))) void*)(gptr),  \
    (__attribute__((address_space(3))) void*)(lptr), 16, 0, 0)

__device__ __forceinline__ unsigned short f2bf(float v) {
    unsigned int u = __float_as_uint(v);
    u += 0x7fffu + ((u >> 16) & 1u);   // RNE
    return (unsigned short)(u >> 16);
}

// Fused: img -> bf16 (pre-scaled by logit_scale*log2e), txt -> bf16,
// exact fp32 diag[i] = scale * dot(img[i], txt[i]), zero-init of the
// row/col sum accumulators. One block per row.
__global__ void preprocess_kernel(const float* __restrict__ img,
                                  const float* __restrict__ txt,
                                  const float* __restrict__ scale_p,
                                  short* __restrict__ imgbf,
                                  short* __restrict__ txtbf,
                                  float* __restrict__ diag,
                                  float* __restrict__ row_sum,
                                  float* __restrict__ col_sum) {
    const int row = blockIdx.x;
    const int tid = threadIdx.x;
    const float sc = *scale_p;
    const float f  = sc * 1.44269504088896340736f;   // fold log2(e) for exp2 epilogue

    const float4 x = ((const float4*)(img + (size_t)row * D_DIM))[tid];
    const float4 y = ((const float4*)(txt + (size_t)row * D_DIM))[tid];

    short4 oi, ot;
    oi.x = (short)f2bf(x.x * f); oi.y = (short)f2bf(x.y * f);
    oi.z = (short)f2bf(x.z * f); oi.w = (short)f2bf(x.w * f);
    ot.x = (short)f2bf(y.x);     ot.y = (short)f2bf(y.y);
    ot.z = (short)f2bf(y.z);     ot.w = (short)f2bf(y.w);
    ((short4*)(imgbf + (size_t)row * D_DIM))[tid] = oi;
    ((short4*)(txtbf + (size_t)row * D_DIM))[tid] = ot;

    float s = x.x * y.x + x.y * y.y + x.z * y.z + x.w * y.w;
#pragma unroll
    for (int m = 1; m < 64; m <<= 1) s += __shfl_xor(s, m);
    __shared__ float ws[4];
    if ((tid & 63) == 0) ws[tid >> 6] = s;
    __syncthreads();
    if (tid == 0) {
        diag[row]    = (ws[0] + ws[1] + ws[2] + ws[3]) * sc;
        row_sum[row] = 0.f;
        col_sum[row] = 0.f;
    }
}

// Round-6 structure (128x128 tile, 4 waves, BK=64, global_load_lds with
// XOR-swizzled source, ~3 blocks/CU implicit overlap) with the inner MFMA
// switched 16x16x32 -> 32x32x16: identical LDS traffic, HALF the MFMA
// instruction count, higher matrix-pipe ceiling (2382 vs 2075 TF, m06).
// Per wave: 64x64 output = 2x2 tiles of 32x32; acc = 4 x f32x16.
__global__ void gemm_exp_kernel(const short* __restrict__ A,   // img bf16, scaled
                                const short* __restrict__ B,   // txt bf16
                                float* __restrict__ row_sum,
                                float* __restrict__ col_sum) {
    __shared__ __align__(16) short As[128 * BK];
    __shared__ __align__(16) short Bs[128 * BK];

    const int tid  = threadIdx.x;
    const int lane = tid & 63;
    const int w    = tid >> 6;      // wave 0..3
    const int wr   = w >> 1;        // wave row (0..1)
    const int wc   = w & 1;         // wave col (0..1)
    const int ti   = blockIdx.y * 128;
    const int tj   = blockIdx.x * 128;

    const int l31 = lane & 31;      // operand row/col within 32-tile
    const int kh  = lane >> 5;      // k-half (0..1): k = kh*8 + e

    // staging: lane -> (row-within-chunk, swizzled k-chunk)  [identical to R6]
    const int srow = lane >> 3;               // 0..7
    const int sg   = (lane & 7) ^ srow;       // global 16B k-chunk after XOR swizzle

    f32x16 acc[2][2];
#pragma unroll
    for (int i = 0; i < 2; i++)
#pragma unroll
        for (int j = 0; j < 2; j++)
#pragma unroll
            for (int r = 0; r < 16; r++) acc[i][j][r] = 0.f;

    const int arow = wr * 64 + l31;   // + tr*32 -> LDS row for a-frag
    const int brow = wc * 64 + l31;   // + tc*32 -> LDS row for b-frag
    const int kcs  = l31 & 7;         // read-side XOR (row & 7, tile-offset invariant)

    for (int k0 = 0; k0 < D_DIM; k0 += BK) {
        // ---- stage A,B tiles (each wave: 4 chunks of 1KB per tile) ----
#pragma unroll
        for (int c = 0; c < 4; c++) {
            const int ch = w * 4 + c;             // 0..15, wave-uniform
            const int r  = ch * 8 + srow;         // tile row 0..127
            const short* ga = A + (size_t)(ti + r) * D_DIM + k0 + sg * 8;
            const short* gb = B + (size_t)(tj + r) * D_DIM + k0 + sg * 8;
            GLD16(ga, As + ch * 512);
            GLD16(gb, Bs + ch * 512);
        }
        __syncthreads();
        // ---- compute: 4 k-steps of 16; 4 MFMA each ----
#pragma unroll
        for (int ks = 0; ks < 4; ks++) {
            const int kc = ((ks << 1) + kh) ^ kcs;   // swizzled 16B chunk
            bf16x8 a0 = *(const bf16x8*)(As + arow * BK + kc * 8);
            bf16x8 a1 = *(const bf16x8*)(As + (arow + 32) * BK + kc * 8);
            bf16x8 b0 = *(const bf16x8*)(Bs + brow * BK + kc * 8);
            bf16x8 b1 = *(const bf16x8*)(Bs + (brow + 32) * BK + kc * 8);
            acc[0][0] = __builtin_amdgcn_mfma_f32_32x32x16_bf16(a0, b0, acc[0][0], 0, 0, 0);
            acc[0][1] = __builtin_amdgcn_mfma_f32_32x32x16_bf16(a0, b1, acc[0][1], 0, 0, 0);
            acc[1][0] = __builtin_amdgcn_mfma_f32_32x32x16_bf16(a1, b0, acc[1][0], 0, 0, 0);
            acc[1][1] = __builtin_amdgcn_mfma_f32_32x32x16_bf16(a1, b1, acc[1][1], 0, 0, 0);
        }
        __syncthreads();
    }

    // ---- epilogue: e = 2^acc, then row/col reductions ----
    // element (tr,tc,j): row = ti + wr*64 + tr*32 + (j&3) + 8*(j>>2) + 4*kh
    //                    col = tj + wc*64 + tc*32 + l31
#pragma unroll
    for (int tr = 0; tr < 2; tr++)
#pragma unroll
        for (int tc = 0; tc < 2; tc++)
#pragma unroll
            for (int j = 0; j < 16; j++)
                acc[tr][tc][j] = __builtin_amdgcn_exp2f(acc[tr][tc][j]);

    // row sums: fixed (tr,j,kh) is one output row across 32 lanes (cols)
    const int rowbase = ti + wr * 64 + 4 * kh;
#pragma unroll
    for (int tr = 0; tr < 2; tr++) {
#pragma unroll
        for (int j = 0; j < 16; j++) {
            float s = acc[tr][0][j] + acc[tr][1][j];
            s += __shfl_xor(s, 1);
            s += __shfl_xor(s, 2);
            s += __shfl_xor(s, 4);
            s += __shfl_xor(s, 8);
            s += __shfl_xor(s, 16);
            if (l31 == 0)
                atomicAdd(&row_sum[rowbase + tr * 32 + (j & 3) + 8 * (j >> 2)], s);
        }
    }

    // col sums: lane l31 owns one column per tc; combine kh halves
    const int colbase = tj + wc * 64;
#pragma unroll
    for (int tc = 0; tc < 2; tc++) {
        float s = 0.f;
#pragma unroll
        for (int tr = 0; tr < 2; tr++)
#pragma unroll
            for (int j = 0; j < 16; j++) s += acc[tr][tc][j];
        s += __shfl_xor(s, 32);
        if (kh == 0)
            atomicAdd(&col_sum[colbase + tc * 32 + l31], s);
    }
}

__global__ void finish_kernel(const float* __restrict__ rs, const float* __restrict__ cs,
                              const float* __restrict__ diag, float* __restrict__ out) {
    const int tid  = threadIdx.x;
    const int lane = tid & 63;
    const int w    = tid >> 6;
    float s = 0.f;
    for (int i = tid; i < N_ROWS; i += 256)
        s += logf(rs[i]) + logf(cs[i]) - 2.0f * diag[i];
#pragma unroll
    for (int m = 1; m < 64; m <<= 1) s += __shfl_xor(s, m);
    __shared__ float wsum[4];
    if (lane == 0) wsum[w] = s;
    __syncthreads();
    if (tid == 0)
        out[0] = (wsum[0] + wsum[1] + wsum[2] + wsum[3]) * (0.5f / (float)N_ROWS);
}

extern "C" void kernel_launch(void* const* d_in, const int* in_sizes, int n_in,
                              void* d_out, int out_size, void* d_ws, size_t ws_size,
                              hipStream_t stream) {
    const float* img     = (const float*)d_in[0];
    const float* txt     = (const float*)d_in[1];
    const float* scale_p = (const float*)d_in[2];
    float* out = (float*)d_out;

    char* ws = (char*)d_ws;
    short* imgbf   = (short*)ws;                                  // 16 MB
    short* txtbf   = (short*)(ws + (size_t)16 * 1024 * 1024);     // 16 MB
    float* row_sum = (float*)(ws + (size_t)32 * 1024 * 1024);     // 32 KB
    float* col_sum = row_sum + N_ROWS;                            // 32 KB
    float* diag    = col_sum + N_ROWS;                            // 32 KB

    preprocess_kernel<<<N_ROWS, 256, 0, stream>>>(img, txt, scale_p, imgbf, txtbf,
                                                  diag, row_sum, col_sum);

    dim3 grid(N_ROWS / 128, N_ROWS / 128);
    gemm_exp_kernel<<<grid, 256, 0, stream>>>(imgbf, txtbf, row_sum, col_sum);

    finish_kernel<<<1, 256, 0, stream>>>(row_sum, col_sum, diag, out);
}

// Round 9
// 203.881 us; speedup vs baseline: 1.5973x; 1.5973x over previous
//
#include <hip/hip_runtime.h>
#include <stdint.h>

#define N_ROWS 8192
#define D_DIM  1024
#define QS     640.0f     // i8 quantization scale

typedef __attribute__((ext_vector_type(4))) int   i32x4;
typedef __attribute__((ext_vector_type(4))) float f32x4;

#define GLD16(gptr, lptr) __builtin_amdgcn_global_load_lds( \
    (const __attribute__((address_space(1))) void*)(gptr),  \
    (__attribute__((address_space(3))) void*)(lptr), 16, 0, 0)

__device__ __forceinline__ int q8(float v) {
    float c = fminf(fmaxf(v * QS, -127.f), 127.f);
    return (int)__builtin_rintf(c);
}

// Fused: img/txt -> int8 (scale QS), exact fp32 diag, zero-init of sums.
// One block per row; each thread quantizes one float4 of each input.
__global__ void preprocess_kernel(const float* __restrict__ img,
                                  const float* __restrict__ txt,
                                  const float* __restrict__ scale_p,
                                  int* __restrict__ imgq,
                                  int* __restrict__ txtq,
                                  float* __restrict__ diag,
                                  float* __restrict__ row_sum,
                                  float* __restrict__ col_sum) {
    const int row = blockIdx.x;
    const int tid = threadIdx.x;

    const float4 x = ((const float4*)(img + (size_t)row * D_DIM))[tid];
    const float4 y = ((const float4*)(txt + (size_t)row * D_DIM))[tid];

    const int pi = (q8(x.x) & 0xFF) | ((q8(x.y) & 0xFF) << 8) |
                   ((q8(x.z) & 0xFF) << 16) | (q8(x.w) << 24);
    const int pt = (q8(y.x) & 0xFF) | ((q8(y.y) & 0xFF) << 8) |
                   ((q8(y.z) & 0xFF) << 16) | (q8(y.w) << 24);
    imgq[(size_t)row * 256 + tid] = pi;
    txtq[(size_t)row * 256 + tid] = pt;

    float s = x.x * y.x + x.y * y.y + x.z * y.z + x.w * y.w;
#pragma unroll
    for (int m = 1; m < 64; m <<= 1) s += __shfl_xor(s, m);
    __shared__ float ws[4];
    if ((tid & 63) == 0) ws[tid >> 6] = s;
    __syncthreads();
    if (tid == 0) {
        diag[row]    = (ws[0] + ws[1] + ws[2] + ws[3]) * (*scale_p);
        row_sum[row] = 0.f;
        col_sum[row] = 0.f;
    }
}

// Round-6 structure with int8 MFMA (16x16x64). Byte-level addressing is
// IDENTICAL to the verified bf16 kernel (128B rows, 16B chunks, XOR swizzle,
// kc = ((kk<<2)+quad)^(row&7)) -> empirically conflict-free. Each 16B chunk
// now carries K=16 elements: 8 K-steps instead of 16, half the staging,
// half the ds_reads, i8 MFMA at ~2x bf16 rate. Accum is exact i32;
// epilogue dequantizes: logit_log2e = acc * (scale*log2e/QS^2).
__global__ void gemm_exp_kernel(const char* __restrict__ A,   // img i8
                                const char* __restrict__ B,   // txt i8
                                const float* __restrict__ scale_p,
                                float* __restrict__ row_sum,
                                float* __restrict__ col_sum) {
    __shared__ __align__(16) char As[128 * 128];
    __shared__ __align__(16) char Bs[128 * 128];

    const float dq = (*scale_p) * (1.44269504088896340736f / (QS * QS));

    const int tid  = threadIdx.x;
    const int lane = tid & 63;
    const int w    = tid >> 6;      // wave 0..3
    const int wr   = w >> 1;        // wave row (0..1)
    const int wc   = w & 1;         // wave col (0..1)
    const int ti   = blockIdx.y * 128;
    const int tj   = blockIdx.x * 128;

    const int quad = lane >> 4;
    const int l15  = lane & 15;

    // staging: lane -> (row-within-chunk, swizzled 16B k-chunk)  [== round 6]
    const int srow = lane >> 3;               // 0..7
    const int sg   = (lane & 7) ^ srow;       // global 16B k-chunk after XOR swizzle

    i32x4 acc[4][4];
#pragma unroll
    for (int i = 0; i < 4; i++)
#pragma unroll
        for (int j = 0; j < 4; j++) acc[i][j] = (i32x4){0, 0, 0, 0};

    const int arow = wr * 64 + l15;   // + fr*16 -> LDS row for a-frag
    const int brow = wc * 64 + l15;   // + fc*16 -> LDS row for b-frag

    for (int k0 = 0; k0 < D_DIM; k0 += 128) {     // 128 i8 per LDS tile row
        // ---- stage A,B tiles (each wave: 4 chunks of 1KB per tile) ----
#pragma unroll
        for (int c = 0; c < 4; c++) {
            const int ch = w * 4 + c;             // 0..15, wave-uniform
            const int r  = ch * 8 + srow;         // tile row 0..127
            const char* ga = A + (size_t)(ti + r) * D_DIM + k0 + sg * 16;
            const char* gb = B + (size_t)(tj + r) * D_DIM + k0 + sg * 16;
            GLD16(ga, As + ch * 1024);
            GLD16(gb, Bs + ch * 1024);
        }
        __syncthreads();
        // ---- compute: 2 kk of K=64; 16 MFMA each ----
#pragma unroll
        for (int kk = 0; kk < 2; kk++) {
            i32x4 af[4], bfb[4];
#pragma unroll
            for (int fr = 0; fr < 4; fr++) {
                const int row = arow + fr * 16;
                const int kc  = ((kk << 2) + quad) ^ (row & 7);
                af[fr] = *(const i32x4*)(As + row * 128 + kc * 16);
            }
#pragma unroll
            for (int fc = 0; fc < 4; fc++) {
                const int row = brow + fc * 16;
                const int kc  = ((kk << 2) + quad) ^ (row & 7);
                bfb[fc] = *(const i32x4*)(Bs + row * 128 + kc * 16);
            }
#pragma unroll
            for (int fr = 0; fr < 4; fr++)
#pragma unroll
                for (int fc = 0; fc < 4; fc++)
                    acc[fr][fc] = __builtin_amdgcn_mfma_i32_16x16x64_i8(
                        af[fr], bfb[fc], acc[fr][fc], 0, 0, 0);
        }
        __syncthreads();
    }

    // ---- epilogue: e = 2^(acc*dq), then row/col reductions ----
    float e[4][4][4];
#pragma unroll
    for (int fr = 0; fr < 4; fr++)
#pragma unroll
        for (int fc = 0; fc < 4; fc++)
#pragma unroll
            for (int r = 0; r < 4; r++)
                e[fr][fc][r] = __builtin_amdgcn_exp2f((float)acc[fr][fc][r] * dq);

    // element (fr,fc,r) = logits[ti + wr*64 + fr*16 + quad*4 + r][tj + wc*64 + fc*16 + l15]
    const int rowbase = ti + wr * 64;
#pragma unroll
    for (int fr = 0; fr < 4; fr++) {
#pragma unroll
        for (int r = 0; r < 4; r++) {
            float s = e[fr][0][r] + e[fr][1][r] + e[fr][2][r] + e[fr][3][r];
            s += __shfl_xor(s, 1);
            s += __shfl_xor(s, 2);
            s += __shfl_xor(s, 4);
            s += __shfl_xor(s, 8);
            if (l15 == 0)
                atomicAdd(&row_sum[rowbase + fr * 16 + quad * 4 + r], s);
        }
    }

    const int colbase = tj + wc * 64;
#pragma unroll
    for (int fc = 0; fc < 4; fc++) {
        float s = 0.f;
#pragma unroll
        for (int fr = 0; fr < 4; fr++)
#pragma unroll
            for (int r = 0; r < 4; r++) s += e[fr][fc][r];
        s += __shfl_xor(s, 16);
        s += __shfl_xor(s, 32);
        if (quad == 0)
            atomicAdd(&col_sum[colbase + fc * 16 + l15], s);
    }
}

__global__ void finish_kernel(const float* __restrict__ rs, const float* __restrict__ cs,
                              const float* __restrict__ diag, float* __restrict__ out) {
    const int tid  = threadIdx.x;
    const int lane = tid & 63;
    const int w    = tid >> 6;
    float s = 0.f;
    for (int i = tid; i < N_ROWS; i += 256)
        s += logf(rs[i]) + logf(cs[i]) - 2.0f * diag[i];
#pragma unroll
    for (int m = 1; m < 64; m <<= 1) s += __shfl_xor(s, m);
    __shared__ float wsum[4];
    if (lane == 0) wsum[w] = s;
    __syncthreads();
    if (tid == 0)
        out[0] = (wsum[0] + wsum[1] + wsum[2] + wsum[3]) * (0.5f / (float)N_ROWS);
}

extern "C" void kernel_launch(void* const* d_in, const int* in_sizes, int n_in,
                              void* d_out, int out_size, void* d_ws, size_t ws_size,
                              hipStream_t stream) {
    const float* img     = (const float*)d_in[0];
    const float* txt     = (const float*)d_in[1];
    const float* scale_p = (const float*)d_in[2];
    float* out = (float*)d_out;

    char* ws = (char*)d_ws;
    int*   imgq    = (int*)ws;                                    // 8 MB
    int*   txtq    = (int*)(ws + (size_t)8 * 1024 * 1024);        // 8 MB
    float* row_sum = (float*)(ws + (size_t)16 * 1024 * 1024);     // 32 KB
    float* col_sum = row_sum + N_ROWS;                            // 32 KB
    float* diag    = col_sum + N_ROWS;                            // 32 KB

    preprocess_kernel<<<N_ROWS, 256, 0, stream>>>(img, txt, scale_p, imgq, txtq,
                                                  diag, row_sum, col_sum);

    dim3 grid(N_ROWS / 128, N_ROWS / 128);
    gemm_exp_kernel<<<grid, 256, 0, stream>>>((const char*)imgq, (const char*)txtq,
                                              scale_p, row_sum, col_sum);

    finish_kernel<<<1, 256, 0, stream>>>(row_sum, col_sum, diag, out);
}